// Round 7
// baseline (311.295 us; speedup 1.0000x reference)
//
#include <hip/hip_runtime.h>

// AdaptiveConv: out[b,c,h,w] = sum_{idx<25} x[b,c,h+idx/5, w+idx%5] * kernel[b,idx,h,w]
// Shapes: x (8,64,260,260) f32, kernel (8,25,256,256) f32, out (8,64,256,256) f32.
//
// R6: all prior rounds were bound by 3.36 GB of per-channel tap re-reads through
// L1/L2 (compiler sinks "register-cached" taps back into the channel loop;
// pinning failed). Fix: amortize taps via CHANNEL BLOCKING in accumulators.
//  - thread = 4 adjacent cols x 1 row x 16 channels; acc[16] float4 (64 VGPR).
//    Accumulators can't be rematerialized -> guaranteed register-resident.
//  - taps transient: per tap-row i, 5 float4 (20 regs) reused across 16 channels,
//    then discarded. Tap cache traffic /16 = 210 MB.
//  - x: per (i,ch) one 8-float row segment = 2 aligned float4 -> 20 FMAs.
//  - grid (64,8,4): 4 channel-groups; each x plane read by exactly one group.

constexpr int K  = 5;
constexpr int B  = 8;
constexpr int C  = 64;
constexpr int H  = 256;
constexpr int W  = 256;
constexpr int HX = H + K - 1;   // 260
constexpr int WX = W + K - 1;   // 260

constexpr int CH  = 16;         // channels per thread (acc blocking)
constexpr int NCG = C / CH;     // 4 channel groups (grid.z)
constexpr int HPB = 4;          // output rows per block (one per thread-row)

typedef float f4 __attribute__((ext_vector_type(4)));

__global__ __launch_bounds__(256, 3)
void adaptive_conv_kernel(const float* __restrict__ x,
                          const float* __restrict__ kern,
                          float* __restrict__ out) {
    const int tid = threadIdx.x;
    const int wg  = tid & 63;               // w-group: wave = 64 lanes spanning W
    const int hr  = tid >> 6;               // 0..3 row within block
    const int w0  = wg * 4;                 // 4 adjacent output columns
    const int h   = blockIdx.x * HPB + hr;  // output row
    const int b   = blockIdx.y;
    const int c0  = blockIdx.z * CH;        // channel group base

    f4 acc[CH];
    #pragma unroll
    for (int ch = 0; ch < CH; ++ch) acc[ch] = (f4)0.0f;

    const float* xb = x    + ((size_t)b * C + c0) * (HX * WX) + (size_t)h * WX + w0;
    const float* kb = kern + (size_t)b * (K * K * H * W)      + (size_t)h * W  + w0;

    #pragma unroll
    for (int i = 0; i < K; ++i) {
        // Tap row i: 5 float4 (cols w0..w0+3 for j=0..4). Loaded ONCE, reused
        // across all 16 channels. All addresses 16B-aligned (w0 % 4 == 0, all
        // plane/row strides are multiples of 4 floats).
        f4 t[K];
        #pragma unroll
        for (int j = 0; j < K; ++j) {
            t[j] = *(const f4*)(kb + (size_t)(i * K + j) * (H * W));
        }
        // Keep taps from being sunk into the channel loop (R4/R5 lesson).
        #pragma unroll
        for (int j = 0; j < K; ++j) asm volatile("" : "+v"(t[j]));

        #pragma unroll
        for (int ch = 0; ch < CH; ++ch) {
            // x row segment: cols w0..w0+7 = two aligned float4.
            const float* xr = xb + (size_t)ch * (HX * WX) + (size_t)i * WX;
            f4 xa = *(const f4*)(xr);
            f4 xc = *(const f4*)(xr + 4);
            float xs[8] = {xa.x, xa.y, xa.z, xa.w, xc.x, xc.y, xc.z, xc.w};

            #pragma unroll
            for (int j = 0; j < K; ++j) {
                acc[ch].x = fmaf(xs[0 + j], t[j].x, acc[ch].x);
                acc[ch].y = fmaf(xs[1 + j], t[j].y, acc[ch].y);
                acc[ch].z = fmaf(xs[2 + j], t[j].z, acc[ch].z);
                acc[ch].w = fmaf(xs[3 + j], t[j].w, acc[ch].w);
            }
        }
    }

    float* ob = out + ((size_t)b * C + c0) * (H * W) + (size_t)h * W + w0;
    #pragma unroll
    for (int ch = 0; ch < CH; ++ch) {
        // out written once, never read: bypass caches.
        __builtin_nontemporal_store(acc[ch], (f4*)(ob + (size_t)ch * (H * W)));
    }
}

extern "C" void kernel_launch(void* const* d_in, const int* in_sizes, int n_in,
                              void* d_out, int out_size, void* d_ws, size_t ws_size,
                              hipStream_t stream) {
    const float* x    = (const float*)d_in[0];
    const float* kern = (const float*)d_in[1];
    float*       out  = (float*)d_out;

    dim3 grid(H / HPB, B, NCG);   // 64 x 8 x 4 = 2048 blocks
    dim3 block(256);              // 64 w-groups x 4 rows
    adaptive_conv_kernel<<<grid, block, 0, stream>>>(x, kern, out);
}

// Round 8
// 163.393 us; speedup vs baseline: 1.9052x; 1.9052x over previous
//
#include <hip/hip_runtime.h>

// AdaptiveConv: out[b,c,h,w] = sum_{idx<25} x[b,c,h+idx/5, w+idx%5] * kernel[b,idx,h,w]
// Shapes: x (8,64,260,260) f32, kernel (8,25,256,256) f32, out (8,64,256,256) f32.
//
// R7: R6's channel-blocking idea was right (divides the 3.36 GB tap stream by CH)
// but acc[16]f4 + asm-pinned f4 taps spilled (WRITE 516MB vs 131MB output, VGPR 84,
// 4.9% VALUBusy). Fix: CH=8 (acc = 32 VGPR), NO asm pins — in a fully unrolled
// body each tap load exists once and cannot be duplicated, so register residency
// doesn't need forcing. Peak live ~85 VGPR, well under the (256,3) cap.
//  - thread = 4 adjacent cols x 1 row x 8 channels; acc[8] float4.
//  - taps: per tap-row i, 5 float4 reused across 8 unrolled channels.
//  - x: per (i,ch) one 8-float segment = 2 aligned float4 -> 20 FMAs.
//  - grid (64,8,8): tap-sharing blocks (same x,y; z varies) are 512 apart in
//    dispatch order -> same XCD (512%8==0) -> kern re-reads hit the same L2.

constexpr int K  = 5;
constexpr int B  = 8;
constexpr int C  = 64;
constexpr int H  = 256;
constexpr int W  = 256;
constexpr int HX = H + K - 1;   // 260
constexpr int WX = W + K - 1;   // 260

constexpr int CH  = 8;          // channels per thread (acc blocking)
constexpr int NCG = C / CH;     // 8 channel groups (grid.z)
constexpr int HPB = 4;          // output rows per block (one per 64-lane slice)

typedef float f4 __attribute__((ext_vector_type(4)));

__global__ __launch_bounds__(256, 3)
void adaptive_conv_kernel(const float* __restrict__ x,
                          const float* __restrict__ kern,
                          float* __restrict__ out) {
    const int tid = threadIdx.x;
    const int wg  = tid & 63;               // lane within wave; wave spans full W
    const int hr  = tid >> 6;               // 0..3: row slice within block
    const int w0  = wg * 4;                 // 4 adjacent output columns (16B aligned)
    const int h   = blockIdx.x * HPB + hr;  // output row
    const int b   = blockIdx.y;
    const int c0  = blockIdx.z * CH;        // channel group base

    f4 acc[CH];
    #pragma unroll
    for (int ch = 0; ch < CH; ++ch) acc[ch] = (f4)0.0f;

    const float* xb = x    + ((size_t)b * C + c0) * (HX * WX) + (size_t)h * WX + w0;
    const float* kb = kern + (size_t)b * (K * K * H * W)      + (size_t)h * W  + w0;

    #pragma unroll
    for (int i = 0; i < K; ++i) {
        // Tap row i: 5 float4 (my 4 cols for j=0..4), reused across 8 channels.
        // All 16B aligned: w0 % 4 == 0 and every stride is a multiple of 4 floats.
        f4 t[K];
        #pragma unroll
        for (int j = 0; j < K; ++j) {
            t[j] = *(const f4*)(kb + (size_t)(i * K + j) * (H * W));
        }

        #pragma unroll
        for (int ch = 0; ch < CH; ++ch) {
            // x row segment: cols w0..w0+7 = two aligned float4 (coalesced; the
            // +4 load hits the neighbor lane's line in L1).
            const float* xr = xb + (size_t)ch * (HX * WX) + (size_t)i * WX;
            f4 xa = *(const f4*)(xr);
            f4 xcv = *(const f4*)(xr + 4);
            float xs[8] = {xa.x, xa.y, xa.z, xa.w, xcv.x, xcv.y, xcv.z, xcv.w};

            #pragma unroll
            for (int j = 0; j < K; ++j) {      // static indices only (rule #20)
                acc[ch].x = fmaf(xs[j + 0], t[j].x, acc[ch].x);
                acc[ch].y = fmaf(xs[j + 1], t[j].y, acc[ch].y);
                acc[ch].z = fmaf(xs[j + 2], t[j].z, acc[ch].z);
                acc[ch].w = fmaf(xs[j + 3], t[j].w, acc[ch].w);
            }
        }
    }

    float* ob = out + ((size_t)b * C + c0) * (H * W) + (size_t)h * W + w0;
    #pragma unroll
    for (int ch = 0; ch < CH; ++ch) {
        // out written once, never read: bypass caches.
        __builtin_nontemporal_store(acc[ch], (f4*)(ob + (size_t)ch * (H * W)));
    }
}

extern "C" void kernel_launch(void* const* d_in, const int* in_sizes, int n_in,
                              void* d_out, int out_size, void* d_ws, size_t ws_size,
                              hipStream_t stream) {
    const float* x    = (const float*)d_in[0];
    const float* kern = (const float*)d_in[1];
    float*       out  = (float*)d_out;

    dim3 grid(H / HPB, B, NCG);   // 64 x 8 x 8 = 4096 blocks
    dim3 block(256);              // 4 row-slices x 64 lanes
    adaptive_conv_kernel<<<grid, block, 0, stream>>>(x, kern, out);
}

// Round 9
// 79.636 us; speedup vs baseline: 3.9090x; 2.0517x over previous
//
#include <hip/hip_runtime.h>

// AdaptiveConv: out[b,c,h,w] = sum_{idx<25} x[b,c,h+idx/5, w+idx%5] * kernel[b,idx,h,w]
// Shapes: x (8,64,260,260) f32, kernel (8,25,256,256) f32, out (8,64,256,256) f32.
//
// R8: R7's inner loop is good (no spill, WRITE=131MB) but FETCH=472MB vs 190MB
// footprint: kern re-read x8 by channel groups + x halo re-read x2, with sharers
// far apart in dispatch order -> no L2 reuse. Fix = locality-only (inner loop
// untouched):
//  - logical order: cg fastest (orig = b*512 + hblk*8 + cg) so the 8 blocks
//    sharing one 102KB kern tile are CONSECUTIVE logical ids.
//  - m157 XCD swizzle: orig = (k&7)*(nwg/8) + (k>>3). XCD r (hw ids = r mod 8)
//    then runs logical ids r*512..r*512+511 back-to-back -> kern tile stays in
//    that XCD's 4MB L2 (resident set ~1.6MB); adjacent-hblk x halo also L2-hits.

constexpr int K  = 5;
constexpr int B  = 8;
constexpr int C  = 64;
constexpr int H  = 256;
constexpr int W  = 256;
constexpr int HX = H + K - 1;   // 260
constexpr int WX = W + K - 1;   // 260

constexpr int CH  = 8;          // channels per thread (acc blocking)
constexpr int NCG = C / CH;     // 8 channel groups
constexpr int HPB = 4;          // output rows per block (one per 64-lane slice)
constexpr int NHB = H / HPB;    // 64 h-blocks
constexpr int NWG = NHB * B * NCG;  // 4096 blocks

typedef float f4 __attribute__((ext_vector_type(4)));

__global__ __launch_bounds__(256, 3)
void adaptive_conv_kernel(const float* __restrict__ x,
                          const float* __restrict__ kern,
                          float* __restrict__ out) {
    // XCD-aware swizzle (bijective: NWG % 8 == 0). Hardware round-robins hw id
    // k across 8 XCDs; logical ids are assigned so one XCD sweeps a contiguous
    // 512-id chunk in order. cg is the fastest logical index -> the 8 blocks
    // sharing a kern tile run consecutively on one XCD.
    const int k    = blockIdx.x;
    const int orig = (k & 7) * (NWG / 8) + (k >> 3);
    const int cg   = orig & (NCG - 1);          // channel group (fastest)
    const int hblk = (orig >> 3) & (NHB - 1);   // h-block
    const int b    = orig >> 9;                 // batch (slowest)

    const int tid = threadIdx.x;
    const int wg  = tid & 63;               // lane within wave; wave spans full W
    const int hr  = tid >> 6;               // 0..3: row slice within block
    const int w0  = wg * 4;                 // 4 adjacent output columns (16B aligned)
    const int h   = hblk * HPB + hr;        // output row
    const int c0  = cg * CH;                // channel base

    f4 acc[CH];
    #pragma unroll
    for (int ch = 0; ch < CH; ++ch) acc[ch] = (f4)0.0f;

    const float* xb = x    + ((size_t)b * C + c0) * (HX * WX) + (size_t)h * WX + w0;
    const float* kb = kern + (size_t)b * (K * K * H * W)      + (size_t)h * W  + w0;

    #pragma unroll
    for (int i = 0; i < K; ++i) {
        // Tap row i: 5 float4 (my 4 cols for j=0..4), reused across 8 channels.
        // All 16B aligned: w0 % 4 == 0 and every stride is a multiple of 4 floats.
        f4 t[K];
        #pragma unroll
        for (int j = 0; j < K; ++j) {
            t[j] = *(const f4*)(kb + (size_t)(i * K + j) * (H * W));
        }

        #pragma unroll
        for (int ch = 0; ch < CH; ++ch) {
            // x row segment: cols w0..w0+7 = two aligned float4 (coalesced; the
            // +4 load hits the neighbor lane's line in L1).
            const float* xr = xb + (size_t)ch * (HX * WX) + (size_t)i * WX;
            f4 xa  = *(const f4*)(xr);
            f4 xcv = *(const f4*)(xr + 4);
            float xs[8] = {xa.x, xa.y, xa.z, xa.w, xcv.x, xcv.y, xcv.z, xcv.w};

            #pragma unroll
            for (int j = 0; j < K; ++j) {      // static indices only (rule #20)
                acc[ch].x = fmaf(xs[j + 0], t[j].x, acc[ch].x);
                acc[ch].y = fmaf(xs[j + 1], t[j].y, acc[ch].y);
                acc[ch].z = fmaf(xs[j + 2], t[j].z, acc[ch].z);
                acc[ch].w = fmaf(xs[j + 3], t[j].w, acc[ch].w);
            }
        }
    }

    float* ob = out + ((size_t)b * C + c0) * (H * W) + (size_t)h * W + w0;
    #pragma unroll
    for (int ch = 0; ch < CH; ++ch) {
        // out written once, never read: bypass caches.
        __builtin_nontemporal_store(acc[ch], (f4*)(ob + (size_t)ch * (H * W)));
    }
}

extern "C" void kernel_launch(void* const* d_in, const int* in_sizes, int n_in,
                              void* d_out, int out_size, void* d_ws, size_t ws_size,
                              hipStream_t stream) {
    const float* x    = (const float*)d_in[0];
    const float* kern = (const float*)d_in[1];
    float*       out  = (float*)d_out;

    dim3 grid(NWG);      // 4096 blocks, 1D; decode + swizzle in-kernel
    dim3 block(256);     // 4 row-slices x 64 lanes
    adaptive_conv_kernel<<<grid, block, 0, stream>>>(x, kern, out);
}

// Round 10
// 66.486 us; speedup vs baseline: 4.6821x; 1.1978x over previous
//
#include <hip/hip_runtime.h>

// AdaptiveConv: out[b,c,h,w] = sum_{idx<25} x[b,c,h+idx/5, w+idx%5] * kernel[b,idx,h,w]
// Shapes: x (8,64,260,260) f32, kernel (8,25,256,256) f32, out (8,64,256,256) f32.
//
// R9: R8 fixed HBM locality (FETCH 472->141MB) but left 1.34 GB of x re-reads
// flowing through per-XCD L2 (~39us) co-bound with the 44us HBM stream.
// Fix: stage the block's x tile (8ch x 8rows x 260 = 66.6KB) in LDS once;
// the 80 x-reads/thread then come from LDS (69 TB/s, ~19us, hidden). L2 now
// carries only x-fill (273MB) + taps (420MB) ~= 0.7GB (~18us) < HBM floor.
// Taps have zero intra-block reuse -> stay direct L2 reads (stage only reused
// data). Inner loop / CH=8 / R8 XCD-swizzle unchanged (locality-only edit).

constexpr int K  = 5;
constexpr int B  = 8;
constexpr int C  = 64;
constexpr int H  = 256;
constexpr int W  = 256;
constexpr int HX = H + K - 1;   // 260
constexpr int WX = W + K - 1;   // 260

constexpr int CH  = 8;          // channels per thread (acc blocking)
constexpr int NCG = C / CH;     // 8 channel groups
constexpr int HPB = 4;          // output rows per block (one per 64-lane slice)
constexpr int NHB = H / HPB;    // 64 h-blocks
constexpr int NWG = NHB * B * NCG;  // 4096 blocks

constexpr int XROWS     = HPB + K - 1;      // 8 x-rows per block
constexpr int CH_FLOATS = XROWS * WX;       // 2080 floats = 8320 B per channel
constexpr int LDS_FLOATS = CH * CH_FLOATS;  // 16640 floats = 66,560 B (gfx950: 160KB/CU)

typedef float f4 __attribute__((ext_vector_type(4)));

__global__ __launch_bounds__(256, 2)
void adaptive_conv_kernel(const float* __restrict__ x,
                          const float* __restrict__ kern,
                          float* __restrict__ out) {
    __shared__ float xs[LDS_FLOATS];

    // XCD-aware swizzle (bijective: NWG % 8 == 0); cg fastest so the 8 blocks
    // sharing one kern tile run consecutively on one XCD (R8, FETCH-verified).
    const int k    = blockIdx.x;
    const int orig = (k & 7) * (NWG / 8) + (k >> 3);
    const int cg   = orig & (NCG - 1);          // channel group (fastest)
    const int hblk = (orig >> 3) & (NHB - 1);   // h-block
    const int b    = orig >> 9;                 // batch (slowest)

    const int tid  = threadIdx.x;
    const int lane = tid & 63;               // lane within wave; wave spans full W
    const int wv   = tid >> 6;               // 0..3: wave id = row slice
    const int w0   = lane * 4;               // 4 adjacent output columns (16B aligned)
    const int h    = hblk * HPB + wv;        // output row
    const int c0   = cg * CH;                // channel base

    const size_t xplane = (size_t)HX * WX;
    // ---- stage x[b, c0:c0+8, h0:h0+8, 0:260] -> LDS (66.6 KB, once) ----
    // Each wave stages 2 channels; per channel 2080 contiguous floats =
    // 8 full-wave f4 sweeps (1 KiB each) + one 8-lane tail (128 B).
    {
        const float* xg0 = x + ((size_t)b * C + c0) * xplane
                             + (size_t)(hblk * HPB) * WX;
        #pragma unroll
        for (int cc = 0; cc < 2; ++cc) {
            const int ch = wv * 2 + cc;
            const float* src = xg0 + (size_t)ch * xplane;
            float*       dst = &xs[ch * CH_FLOATS];
            #pragma unroll
            for (int t = 0; t < 8; ++t) {
                f4 v = *(const f4*)(src + t * 256 + lane * 4);  // coalesced, f4-aligned
                *(f4*)(dst + t * 256 + lane * 4) = v;           // sequential: conflict-free
            }
            if (lane < 8) {
                f4 v = *(const f4*)(src + 2048 + lane * 4);
                *(f4*)(dst + 2048 + lane * 4) = v;
            }
        }
    }
    __syncthreads();

    f4 acc[CH];
    #pragma unroll
    for (int ch = 0; ch < CH; ++ch) acc[ch] = (f4)0.0f;

    const float* kb = kern + (size_t)b * (K * K * H * W) + (size_t)h * W + w0;

    #pragma unroll
    for (int i = 0; i < K; ++i) {
        // Tap row i: 5 float4 (my 4 cols, j=0..4), reused across 8 channels.
        // Only remaining global reads in the loop; L2-resident via R8 swizzle.
        f4 t[K];
        #pragma unroll
        for (int j = 0; j < K; ++j) {
            t[j] = *(const f4*)(kb + (size_t)(i * K + j) * (H * W));
        }

        #pragma unroll
        for (int ch = 0; ch < CH; ++ch) {
            // x row segment from LDS: cols w0..w0+7 of x-row (wv+i).
            // byte addr = 16*lane + const -> sequential 16B/lane, conflict-free.
            const float* xr = &xs[ch * CH_FLOATS + (wv + i) * WX + w0];
            f4 xa  = *(const f4*)(xr);
            f4 xcv = *(const f4*)(xr + 4);
            float xsg[8] = {xa.x, xa.y, xa.z, xa.w, xcv.x, xcv.y, xcv.z, xcv.w};

            #pragma unroll
            for (int j = 0; j < K; ++j) {      // static indices only (rule #20)
                acc[ch].x = fmaf(xsg[j + 0], t[j].x, acc[ch].x);
                acc[ch].y = fmaf(xsg[j + 1], t[j].y, acc[ch].y);
                acc[ch].z = fmaf(xsg[j + 2], t[j].z, acc[ch].z);
                acc[ch].w = fmaf(xsg[j + 3], t[j].w, acc[ch].w);
            }
        }
    }

    float* ob = out + ((size_t)b * C + c0) * (H * W) + (size_t)h * W + w0;
    #pragma unroll
    for (int ch = 0; ch < CH; ++ch) {
        // out written once, never read: bypass caches.
        __builtin_nontemporal_store(acc[ch], (f4*)(ob + (size_t)ch * (H * W)));
    }
}

extern "C" void kernel_launch(void* const* d_in, const int* in_sizes, int n_in,
                              void* d_out, int out_size, void* d_ws, size_t ws_size,
                              hipStream_t stream) {
    const float* x    = (const float*)d_in[0];
    const float* kern = (const float*)d_in[1];
    float*       out  = (float*)d_out;

    dim3 grid(NWG);      // 4096 blocks, 1D; decode + swizzle in-kernel
    dim3 block(256);     // 4 row-slices x 64 lanes
    adaptive_conv_kernel<<<grid, block, 0, stream>>>(x, kern, out);
}

// Round 11
// 65.958 us; speedup vs baseline: 4.7196x; 1.0080x over previous
//
#include <hip/hip_runtime.h>

// AdaptiveConv: out[b,c,h,w] = sum_{idx<25} x[b,c,h+idx/5, w+idx%5] * kernel[b,idx,h,w]
// Shapes: x (8,64,260,260) f32, kernel (8,25,256,256) f32, out (8,64,256,256) f32.
//
// R10: R9 (LDS-staged x) hit 66.5us but at 20% occupancy (66.6KB LDS -> 2
// blocks/CU = 2 waves/SIMD): no pipe saturated, latency unhidden. Fix: CH 8->4
// halves LDS to 33.3KB -> 4 blocks/CU, 16 waves/CU (~40-50% occ), inner loop
// IDENTICAL (two-lane discipline: occupancy-only edit). Cost accepted: tap L2
// traffic x2 = 840MB (~24us, still under the 41us HBM floor).
//  - thread = 4 cols x 1 row x 4 channels; acc[4] float4 (16 VGPR).
//  - x tile 4ch x 8rows x 260 staged in LDS (33.3KB), conflict-free f4 pattern.
//  - R8 XCD swizzle, cg fastest: 16 tap-sharing blocks consecutive on one XCD.

constexpr int K  = 5;
constexpr int B  = 8;
constexpr int C  = 64;
constexpr int H  = 256;
constexpr int W  = 256;
constexpr int HX = H + K - 1;   // 260
constexpr int WX = W + K - 1;   // 260

constexpr int CH  = 4;          // channels per thread (acc blocking)
constexpr int NCG = C / CH;     // 16 channel groups
constexpr int HPB = 4;          // output rows per block (one per 64-lane slice)
constexpr int NHB = H / HPB;    // 64 h-blocks
constexpr int NWG = NHB * B * NCG;  // 8192 blocks

constexpr int XROWS      = HPB + K - 1;      // 8 x-rows per block
constexpr int CH_FLOATS  = XROWS * WX;       // 2080 floats per channel
constexpr int LDS_FLOATS = CH * CH_FLOATS;   // 8320 floats = 33,280 B

typedef float f4 __attribute__((ext_vector_type(4)));

__global__ __launch_bounds__(256, 4)
void adaptive_conv_kernel(const float* __restrict__ x,
                          const float* __restrict__ kern,
                          float* __restrict__ out) {
    __shared__ float xs[LDS_FLOATS];

    // XCD-aware swizzle (bijective: NWG % 8 == 0); cg fastest so the 16 blocks
    // sharing one kern tile run consecutively on one XCD (R8, FETCH-verified).
    const int k    = blockIdx.x;
    const int orig = (k & 7) * (NWG / 8) + (k >> 3);
    const int cg   = orig & (NCG - 1);          // channel group (fastest)
    const int hblk = (orig >> 4) & (NHB - 1);   // h-block
    const int b    = orig >> 10;                // batch (slowest)

    const int tid  = threadIdx.x;
    const int lane = tid & 63;               // lane within wave; wave spans full W
    const int wv   = tid >> 6;               // 0..3: wave id = row slice
    const int w0   = lane * 4;               // 4 adjacent output columns (16B aligned)
    const int h    = hblk * HPB + wv;        // output row
    const int c0   = cg * CH;                // channel base

    const size_t xplane = (size_t)HX * WX;
    // ---- stage x[b, c0:c0+4, h0:h0+8, 0:260] -> LDS (33.3 KB, once) ----
    // Wave wv stages channel wv: 2080 floats = 8 full-wave f4 sweeps (1 KiB)
    // + one 8-lane tail (128 B). Coalesced, sequential, conflict-free.
    {
        const float* src = x + ((size_t)b * C + c0 + wv) * xplane
                             + (size_t)(hblk * HPB) * WX;
        float* dst = &xs[wv * CH_FLOATS];
        #pragma unroll
        for (int t = 0; t < 8; ++t) {
            f4 v = *(const f4*)(src + t * 256 + lane * 4);
            *(f4*)(dst + t * 256 + lane * 4) = v;
        }
        if (lane < 8) {
            f4 v = *(const f4*)(src + 2048 + lane * 4);
            *(f4*)(dst + 2048 + lane * 4) = v;
        }
    }
    __syncthreads();

    f4 acc[CH];
    #pragma unroll
    for (int ch = 0; ch < CH; ++ch) acc[ch] = (f4)0.0f;

    const float* kb = kern + (size_t)b * (K * K * H * W) + (size_t)h * W + w0;

    #pragma unroll
    for (int i = 0; i < K; ++i) {
        // Tap row i: 5 float4 (my 4 cols, j=0..4), reused across 4 channels.
        // Only remaining global reads in the loop; L2-resident via swizzle.
        f4 t[K];
        #pragma unroll
        for (int j = 0; j < K; ++j) {
            t[j] = *(const f4*)(kb + (size_t)(i * K + j) * (H * W));
        }

        #pragma unroll
        for (int ch = 0; ch < CH; ++ch) {
            // x row segment from LDS: cols w0..w0+7 of x-row (wv+i).
            // byte addr = 16*lane + const -> sequential 16B/lane, conflict-free.
            const float* xr = &xs[ch * CH_FLOATS + (wv + i) * WX + w0];
            f4 xa  = *(const f4*)(xr);
            f4 xcv = *(const f4*)(xr + 4);
            float xsg[8] = {xa.x, xa.y, xa.z, xa.w, xcv.x, xcv.y, xcv.z, xcv.w};

            #pragma unroll
            for (int j = 0; j < K; ++j) {      // static indices only (rule #20)
                acc[ch].x = fmaf(xsg[j + 0], t[j].x, acc[ch].x);
                acc[ch].y = fmaf(xsg[j + 1], t[j].y, acc[ch].y);
                acc[ch].z = fmaf(xsg[j + 2], t[j].z, acc[ch].z);
                acc[ch].w = fmaf(xsg[j + 3], t[j].w, acc[ch].w);
            }
        }
    }

    float* ob = out + ((size_t)b * C + c0) * (H * W) + (size_t)h * W + w0;
    #pragma unroll
    for (int ch = 0; ch < CH; ++ch) {
        // out written once, never read: bypass caches.
        __builtin_nontemporal_store(acc[ch], (f4*)(ob + (size_t)ch * (H * W)));
    }
}

extern "C" void kernel_launch(void* const* d_in, const int* in_sizes, int n_in,
                              void* d_out, int out_size, void* d_ws, size_t ws_size,
                              hipStream_t stream) {
    const float* x    = (const float*)d_in[0];
    const float* kern = (const float*)d_in[1];
    float*       out  = (float*)d_out;

    dim3 grid(NWG);      // 8192 blocks, 1D; decode + swizzle in-kernel
    dim3 block(256);     // 4 row-slices x 64 lanes
    adaptive_conv_kernel<<<grid, block, 0, stream>>>(x, kern, out);
}

// Round 12
// 65.258 us; speedup vs baseline: 4.7702x; 1.0107x over previous
//
#include <hip/hip_runtime.h>

// AdaptiveConv: out[b,c,h,w] = sum_{idx<25} x[b,c,h+idx/5, w+idx%5] * kernel[b,idx,h,w]
// Shapes: x (8,64,260,260) f32, kernel (8,25,256,256) f32, out (8,64,256,256) f32.
//
// R11: R10 doubled occupancy (20->42%) with dur flat -> not wave-count-bound.
// Diagnosis: exposed L2 latency on the 5 tap loads heading each unrolled
// i-iteration (VGPR=64 => zero prefetch depth kept by the scheduler).
// Fix: depth-1 register pipeline on tap rows — load row i+1 (5 x f4, 20 VGPR)
// while computing row i; row 0 issued BEFORE __syncthreads so it hides under
// LDS staging. Peak live ~95 VGPR < 128 cap at (256,4); occupancy unchanged.
// Inner FMA loop, CH=4, LDS staging, R8 XCD swizzle: all unchanged.

constexpr int K  = 5;
constexpr int B  = 8;
constexpr int C  = 64;
constexpr int H  = 256;
constexpr int W  = 256;
constexpr int HX = H + K - 1;   // 260
constexpr int WX = W + K - 1;   // 260

constexpr int CH  = 4;          // channels per thread (acc blocking)
constexpr int NCG = C / CH;     // 16 channel groups
constexpr int HPB = 4;          // output rows per block (one per 64-lane slice)
constexpr int NHB = H / HPB;    // 64 h-blocks
constexpr int NWG = NHB * B * NCG;  // 8192 blocks

constexpr int XROWS      = HPB + K - 1;      // 8 x-rows per block
constexpr int CH_FLOATS  = XROWS * WX;       // 2080 floats per channel
constexpr int LDS_FLOATS = CH * CH_FLOATS;   // 8320 floats = 33,280 B

typedef float f4 __attribute__((ext_vector_type(4)));

__global__ __launch_bounds__(256, 4)
void adaptive_conv_kernel(const float* __restrict__ x,
                          const float* __restrict__ kern,
                          float* __restrict__ out) {
    __shared__ float xs[LDS_FLOATS];

    // XCD-aware swizzle (bijective: NWG % 8 == 0); cg fastest so the 16 blocks
    // sharing one kern tile run consecutively on one XCD (R8, FETCH-verified).
    const int k    = blockIdx.x;
    const int orig = (k & 7) * (NWG / 8) + (k >> 3);
    const int cg   = orig & (NCG - 1);          // channel group (fastest)
    const int hblk = (orig >> 4) & (NHB - 1);   // h-block
    const int b    = orig >> 10;                // batch (slowest)

    const int tid  = threadIdx.x;
    const int lane = tid & 63;               // lane within wave; wave spans full W
    const int wv   = tid >> 6;               // 0..3: wave id = row slice
    const int w0   = lane * 4;               // 4 adjacent output columns (16B aligned)
    const int h    = hblk * HPB + wv;        // output row
    const int c0   = cg * CH;                // channel base

    const size_t xplane = (size_t)HX * WX;
    const float* kb = kern + (size_t)b * (K * K * H * W) + (size_t)h * W + w0;

    // ---- stage x[b, c0:c0+4, h0:h0+8, 0:260] -> LDS (33.3 KB, once) ----
    // Wave wv stages channel wv: 8 full-wave f4 sweeps + an 8-lane tail.
    {
        const float* src = x + ((size_t)b * C + c0 + wv) * xplane
                             + (size_t)(hblk * HPB) * WX;
        float* dst = &xs[wv * CH_FLOATS];
        #pragma unroll
        for (int t = 0; t < 8; ++t) {
            f4 v = *(const f4*)(src + t * 256 + lane * 4);
            *(f4*)(dst + t * 256 + lane * 4) = v;
        }
        if (lane < 8) {
            f4 v = *(const f4*)(src + 2048 + lane * 4);
            *(f4*)(dst + 2048 + lane * 4) = v;
        }
    }

    // Tap row 0 prefetch: issued before the barrier so its L2 latency hides
    // under the staging waitcnt (the barrier drains vmcnt anyway).
    f4 tcur[K], tnxt[K];
    #pragma unroll
    for (int j = 0; j < K; ++j) {
        tcur[j] = *(const f4*)(kb + (size_t)j * (H * W));
    }

    __syncthreads();

    f4 acc[CH];
    #pragma unroll
    for (int ch = 0; ch < CH; ++ch) acc[ch] = (f4)0.0f;

    #pragma unroll
    for (int i = 0; i < K; ++i) {
        // Depth-1 pipeline: issue tap row i+1 loads, then compute with row i.
        // ~250+ cyc of FMA+LDS per i covers one L2-hit latency.
        if (i + 1 < K) {
            #pragma unroll
            for (int j = 0; j < K; ++j) {
                tnxt[j] = *(const f4*)(kb + (size_t)((i + 1) * K + j) * (H * W));
            }
        }

        #pragma unroll
        for (int ch = 0; ch < CH; ++ch) {
            // x row segment from LDS: cols w0..w0+7 of x-row (wv+i).
            // byte addr = 16*lane + const -> sequential 16B/lane, conflict-free.
            const float* xr = &xs[ch * CH_FLOATS + (wv + i) * WX + w0];
            f4 xa  = *(const f4*)(xr);
            f4 xcv = *(const f4*)(xr + 4);
            float xsg[8] = {xa.x, xa.y, xa.z, xa.w, xcv.x, xcv.y, xcv.z, xcv.w};

            #pragma unroll
            for (int j = 0; j < K; ++j) {      // static indices only (rule #20)
                acc[ch].x = fmaf(xsg[j + 0], tcur[j].x, acc[ch].x);
                acc[ch].y = fmaf(xsg[j + 1], tcur[j].y, acc[ch].y);
                acc[ch].z = fmaf(xsg[j + 2], tcur[j].z, acc[ch].z);
                acc[ch].w = fmaf(xsg[j + 3], tcur[j].w, acc[ch].w);
            }
        }

        if (i + 1 < K) {
            #pragma unroll
            for (int j = 0; j < K; ++j) tcur[j] = tnxt[j];   // renamed away by RA
        }
    }

    float* ob = out + ((size_t)b * C + c0) * (H * W) + (size_t)h * W + w0;
    #pragma unroll
    for (int ch = 0; ch < CH; ++ch) {
        // out written once, never read: bypass caches.
        __builtin_nontemporal_store(acc[ch], (f4*)(ob + (size_t)ch * (H * W)));
    }
}

extern "C" void kernel_launch(void* const* d_in, const int* in_sizes, int n_in,
                              void* d_out, int out_size, void* d_ws, size_t ws_size,
                              hipStream_t stream) {
    const float* x    = (const float*)d_in[0];
    const float* kern = (const float*)d_in[1];
    float*       out  = (float*)d_out;

    dim3 grid(NWG);      // 8192 blocks, 1D; decode + swizzle in-kernel
    dim3 block(256);     // 4 row-slices x 64 lanes
    adaptive_conv_kernel<<<grid, block, 0, stream>>>(x, kern, out);
}

// Round 13
// 64.867 us; speedup vs baseline: 4.7990x; 1.0060x over previous
//
#include <hip/hip_runtime.h>

// AdaptiveConv: out[b,c,h,w] = sum_{idx<25} x[b,c,h+idx/5, w+idx%5] * kernel[b,idx,h,w]
// Shapes: x (8,64,260,260) f32, kernel (8,25,256,256) f32, out (8,64,256,256) f32.
//
// R11: R10 doubled occupancy (20->42%) with dur flat -> not wave-count-bound.
// Diagnosis: exposed L2 latency on the 5 tap loads heading each unrolled
// i-iteration (VGPR=64 => zero prefetch depth kept by the scheduler).
// Fix: depth-1 register pipeline on tap rows — load row i+1 (5 x f4, 20 VGPR)
// while computing row i; row 0 issued BEFORE __syncthreads so it hides under
// LDS staging. Peak live ~95 VGPR < 128 cap at (256,4); occupancy unchanged.
// Inner FMA loop, CH=4, LDS staging, R8 XCD swizzle: all unchanged.

constexpr int K  = 5;
constexpr int B  = 8;
constexpr int C  = 64;
constexpr int H  = 256;
constexpr int W  = 256;
constexpr int HX = H + K - 1;   // 260
constexpr int WX = W + K - 1;   // 260

constexpr int CH  = 4;          // channels per thread (acc blocking)
constexpr int NCG = C / CH;     // 16 channel groups
constexpr int HPB = 4;          // output rows per block (one per 64-lane slice)
constexpr int NHB = H / HPB;    // 64 h-blocks
constexpr int NWG = NHB * B * NCG;  // 8192 blocks

constexpr int XROWS      = HPB + K - 1;      // 8 x-rows per block
constexpr int CH_FLOATS  = XROWS * WX;       // 2080 floats per channel
constexpr int LDS_FLOATS = CH * CH_FLOATS;   // 8320 floats = 33,280 B

typedef float f4 __attribute__((ext_vector_type(4)));

__global__ __launch_bounds__(256, 4)
void adaptive_conv_kernel(const float* __restrict__ x,
                          const float* __restrict__ kern,
                          float* __restrict__ out) {
    __shared__ float xs[LDS_FLOATS];

    // XCD-aware swizzle (bijective: NWG % 8 == 0); cg fastest so the 16 blocks
    // sharing one kern tile run consecutively on one XCD (R8, FETCH-verified).
    const int k    = blockIdx.x;
    const int orig = (k & 7) * (NWG / 8) + (k >> 3);
    const int cg   = orig & (NCG - 1);          // channel group (fastest)
    const int hblk = (orig >> 4) & (NHB - 1);   // h-block
    const int b    = orig >> 10;                // batch (slowest)

    const int tid  = threadIdx.x;
    const int lane = tid & 63;               // lane within wave; wave spans full W
    const int wv   = tid >> 6;               // 0..3: wave id = row slice
    const int w0   = lane * 4;               // 4 adjacent output columns (16B aligned)
    const int h    = hblk * HPB + wv;        // output row
    const int c0   = cg * CH;                // channel base

    const size_t xplane = (size_t)HX * WX;
    const float* kb = kern + (size_t)b * (K * K * H * W) + (size_t)h * W + w0;

    // ---- stage x[b, c0:c0+4, h0:h0+8, 0:260] -> LDS (33.3 KB, once) ----
    // Wave wv stages channel wv: 8 full-wave f4 sweeps + an 8-lane tail.
    {
        const float* src = x + ((size_t)b * C + c0 + wv) * xplane
                             + (size_t)(hblk * HPB) * WX;
        float* dst = &xs[wv * CH_FLOATS];
        #pragma unroll
        for (int t = 0; t < 8; ++t) {
            f4 v = *(const f4*)(src + t * 256 + lane * 4);
            *(f4*)(dst + t * 256 + lane * 4) = v;
        }
        if (lane < 8) {
            f4 v = *(const f4*)(src + 2048 + lane * 4);
            *(f4*)(dst + 2048 + lane * 4) = v;
        }
    }

    // Tap row 0 prefetch: issued before the barrier so its L2 latency hides
    // under the staging waitcnt (the barrier drains vmcnt anyway).
    f4 tcur[K], tnxt[K];
    #pragma unroll
    for (int j = 0; j < K; ++j) {
        tcur[j] = *(const f4*)(kb + (size_t)j * (H * W));
    }

    __syncthreads();

    f4 acc[CH];
    #pragma unroll
    for (int ch = 0; ch < CH; ++ch) acc[ch] = (f4)0.0f;

    #pragma unroll
    for (int i = 0; i < K; ++i) {
        // Depth-1 pipeline: issue tap row i+1 loads, then compute with row i.
        // ~250+ cyc of FMA+LDS per i covers one L2-hit latency.
        if (i + 1 < K) {
            #pragma unroll
            for (int j = 0; j < K; ++j) {
                tnxt[j] = *(const f4*)(kb + (size_t)((i + 1) * K + j) * (H * W));
            }
        }

        #pragma unroll
        for (int ch = 0; ch < CH; ++ch) {
            // x row segment from LDS: cols w0..w0+7 of x-row (wv+i).
            // byte addr = 16*lane + const -> sequential 16B/lane, conflict-free.
            const float* xr = &xs[ch * CH_FLOATS + (wv + i) * WX + w0];
            f4 xa  = *(const f4*)(xr);
            f4 xcv = *(const f4*)(xr + 4);
            float xsg[8] = {xa.x, xa.y, xa.z, xa.w, xcv.x, xcv.y, xcv.z, xcv.w};

            #pragma unroll
            for (int j = 0; j < K; ++j) {      // static indices only (rule #20)
                acc[ch].x = fmaf(xsg[j + 0], tcur[j].x, acc[ch].x);
                acc[ch].y = fmaf(xsg[j + 1], tcur[j].y, acc[ch].y);
                acc[ch].z = fmaf(xsg[j + 2], tcur[j].z, acc[ch].z);
                acc[ch].w = fmaf(xsg[j + 3], tcur[j].w, acc[ch].w);
            }
        }

        if (i + 1 < K) {
            #pragma unroll
            for (int j = 0; j < K; ++j) tcur[j] = tnxt[j];   // renamed away by RA
        }
    }

    float* ob = out + ((size_t)b * C + c0) * (H * W) + (size_t)h * W + w0;
    #pragma unroll
    for (int ch = 0; ch < CH; ++ch) {
        // out written once, never read: bypass caches.
        __builtin_nontemporal_store(acc[ch], (f4*)(ob + (size_t)ch * (H * W)));
    }
}

extern "C" void kernel_launch(void* const* d_in, const int* in_sizes, int n_in,
                              void* d_out, int out_size, void* d_ws, size_t ws_size,
                              hipStream_t stream) {
    const float* x    = (const float*)d_in[0];
    const float* kern = (const float*)d_in[1];
    float*       out  = (float*)d_out;

    dim3 grid(NWG);      // 8192 blocks, 1D; decode + swizzle in-kernel
    dim3 block(256);     // 4 row-slices x 64 lanes
    adaptive_conv_kernel<<<grid, block, 0, stream>>>(x, kern, out);
}